// Round 2
// baseline (191.076 us; speedup 1.0000x reference)
//
#include <hip/hip_runtime.h>
#include <hip/hip_bf16.h>

// Grouped GEMM: out[e,s,o] = sum_i x[e,s,i] * w[e,o,i]
// E=8, S=8192 tokens/expert, O=512, I=1024, fp32 in/out, bf16 MFMA compute.
// R2: BK 64->32 (LDS 64->32 KiB) to lift occupancy 2->4-5 blocks/CU;
//     swizzle adapted to 4-chunk rows via (row>>1)&3.

#define NE 8
#define NO 512
#define NI 1024
#define NS 8192

#define BM 128
#define BN 128
#define BK 32
#define NT (NI / BK)  // 32 K-steps

typedef __attribute__((ext_vector_type(4))) float f32x4;
typedef __attribute__((ext_vector_type(8))) short short8;

__device__ __forceinline__ short8 cvt8(f32x4 a, f32x4 b) {
    short8 r;
    r[0] = (short)__builtin_bit_cast(unsigned short, __float2bfloat16(a[0]));
    r[1] = (short)__builtin_bit_cast(unsigned short, __float2bfloat16(a[1]));
    r[2] = (short)__builtin_bit_cast(unsigned short, __float2bfloat16(a[2]));
    r[3] = (short)__builtin_bit_cast(unsigned short, __float2bfloat16(a[3]));
    r[4] = (short)__builtin_bit_cast(unsigned short, __float2bfloat16(b[0]));
    r[5] = (short)__builtin_bit_cast(unsigned short, __float2bfloat16(b[1]));
    r[6] = (short)__builtin_bit_cast(unsigned short, __float2bfloat16(b[2]));
    r[7] = (short)__builtin_bit_cast(unsigned short, __float2bfloat16(b[3]));
    return r;
}

__global__ __launch_bounds__(256, 4)
void moe_grouped_gemm(const float* __restrict__ X,
                      const float* __restrict__ W,
                      float* __restrict__ Out) {
    // 2048 blocks = 8 experts * 64 mblks * 4 nblks.
    // XCD-chunk swizzle (nwg % 8 == 0, bijective): each XCD owns one expert.
    int bid  = blockIdx.x;
    int swz  = (bid & 7) * 256 + (bid >> 3);
    int e    = swz >> 8;
    int rem  = swz & 255;
    int mblk = rem >> 2;   // nblk inner: 4 siblings share the same A tile
    int nblk = rem & 3;

    const float* Ap = X   + ((size_t)e * NS + (size_t)mblk * BM) * NI;
    const float* Bp = W   + ((size_t)e * NO + (size_t)nblk * BN) * NI;
    float*       Cp = Out + ((size_t)e * NS + (size_t)mblk * BM) * NO + nblk * BN;

    __shared__ short lA[2][BM * BK];   // 8 KiB each buf
    __shared__ short lB[2][BN * BK];   // total 32 KiB -> 4-5 blocks/CU

    const int tid  = threadIdx.x;
    const int lane = tid & 63;
    const int wid  = tid >> 6;
    const int wr   = (wid >> 1) * 64;   // wave row base (2x2 wave grid)
    const int wc   = (wid & 1) * 64;    // wave col base
    const int l15  = lane & 15;
    const int l4   = lane >> 4;         // logical 16B chunk within BK=32 row

    f32x4 acc[4][4];
#pragma unroll
    for (int i = 0; i < 4; ++i)
#pragma unroll
        for (int j = 0; j < 4; ++j)
            acc[i][j] = (f32x4){0.f, 0.f, 0.f, 0.f};

    // Staging: 512 chunks of 8 floats per matrix; id = tid + i*256.
    // row = id>>2 (0..127), fc = id&3 (8-float chunk within row).
    // Swizzle: phys chunk = fc ^ ((row>>1)&3). Rows 0-7 of a 16-lane group
    // then tile all 32 banks exactly once (odd/even rows alternate halves).
    int qr[2], qfc[2], wofs[2];
#pragma unroll
    for (int i = 0; i < 2; ++i) {
        int id  = tid + i * 256;
        qr[i]   = id >> 2;
        qfc[i]  = id & 3;
        wofs[i] = qr[i] * BK + ((qfc[i] ^ ((qr[i] >> 1) & 3)) << 3);
    }

    f32x4 la[2][2], lb[2][2];

#define LOADT(kt)                                                              \
    do {                                                                       \
        const float* ab = Ap + (kt) * BK;                                      \
        const float* bb = Bp + (kt) * BK;                                      \
        _Pragma("unroll") for (int i = 0; i < 2; ++i) {                        \
            const f32x4* pa = (const f32x4*)(ab + (size_t)qr[i] * NI + qfc[i] * 8); \
            la[i][0] = pa[0];                                                  \
            la[i][1] = pa[1];                                                  \
            const f32x4* pb = (const f32x4*)(bb + (size_t)qr[i] * NI + qfc[i] * 8); \
            lb[i][0] = pb[0];                                                  \
            lb[i][1] = pb[1];                                                  \
        }                                                                      \
    } while (0)

#define STAGE(buf)                                                             \
    do {                                                                       \
        _Pragma("unroll") for (int i = 0; i < 2; ++i) {                        \
            *(short8*)&lA[buf][wofs[i]] = cvt8(la[i][0], la[i][1]);            \
            *(short8*)&lB[buf][wofs[i]] = cvt8(lb[i][0], lb[i][1]);            \
        }                                                                      \
    } while (0)

#define COMPUTE(buf)                                                           \
    do {                                                                       \
        short8 af[4], bf_[4];                                                  \
        _Pragma("unroll") for (int mi = 0; mi < 4; ++mi) {                     \
            int row = wr + mi * 16 + l15;                                      \
            int cc  = ((l4 ^ ((row >> 1) & 3)) << 3);                          \
            af[mi]  = *(const short8*)&lA[buf][row * BK + cc];                 \
        }                                                                      \
        _Pragma("unroll") for (int ni = 0; ni < 4; ++ni) {                     \
            int row = wc + ni * 16 + l15;                                      \
            int cc  = ((l4 ^ ((row >> 1) & 3)) << 3);                          \
            bf_[ni] = *(const short8*)&lB[buf][row * BK + cc];                 \
        }                                                                      \
        _Pragma("unroll") for (int mi = 0; mi < 4; ++mi)                       \
            _Pragma("unroll") for (int ni = 0; ni < 4; ++ni)                   \
                acc[mi][ni] = __builtin_amdgcn_mfma_f32_16x16x32_bf16(         \
                    af[mi], bf_[ni], acc[mi][ni], 0, 0, 0);                    \
    } while (0)

    LOADT(0);
    STAGE(0);
    __syncthreads();
    int cur = 0;
#pragma unroll 1
    for (int kt = 0; kt < NT; ++kt) {
        if (kt + 1 < NT) LOADT(kt + 1);      // issue next-tile loads early
        COMPUTE(cur);
        if (kt + 1 < NT) STAGE(cur ^ 1);     // convert + ds_write after compute
        __syncthreads();                     // one barrier per K-step (dbuf)
        cur ^= 1;
    }

    // Epilogue: D[m][n], m = (lane>>4)*4 + r, n = lane&15 within each 16x16 frag.
#pragma unroll
    for (int mi = 0; mi < 4; ++mi) {
#pragma unroll
        for (int r = 0; r < 4; ++r) {
            int row   = wr + mi * 16 + l4 * 4 + r;
            float* cp = Cp + (size_t)row * NO + wc + l15;
#pragma unroll
            for (int ni = 0; ni < 4; ++ni)
                cp[ni * 16] = acc[mi][ni][r];
        }
    }
#undef LOADT
#undef STAGE
#undef COMPUTE
}

extern "C" void kernel_launch(void* const* d_in, const int* in_sizes, int n_in,
                              void* d_out, int out_size, void* d_ws, size_t ws_size,
                              hipStream_t stream) {
    const float* X = (const float*)d_in[0];
    const float* W = (const float*)d_in[1];
    float* Out     = (float*)d_out;
    // d_in[2] (expert_size) is static == 8192; layout is compile-time.
    dim3 grid(NE * (NS / BM) * (NO / BN));  // 2048
    dim3 block(256);
    hipLaunchKernelGGL(moe_grouped_gemm, grid, block, 0, stream, X, W, Out);
}

// Round 3
// 164.931 us; speedup vs baseline: 1.1585x; 1.1585x over previous
//
#include <hip/hip_runtime.h>
#include <hip/hip_bf16.h>

// Grouped GEMM: out[e,s,o] = sum_i x[e,s,i] * w[e,o,i]
// E=8, S=8192 tok/expert, O=512, I=1024, fp32 in/out, bf16 MFMA compute.
// R3: pass0 packs W -> bf16 in MFMA fragment-lane order (d_ws, 8 MB).
//     Main kernel: B fragments loaded reg-direct from L2 (no LDS/cvt for B);
//     LDS holds only A (2x16 KB, BK=64, 16 iters).

#define NE 8
#define NO 512
#define NI 1024
#define NS 8192

#define BM 128
#define BN 128
#define BK 64
#define NT (NI / BK)  // 16 K-steps

typedef __attribute__((ext_vector_type(4))) float f32x4;
typedef __attribute__((ext_vector_type(8))) short short8;

__device__ __forceinline__ short8 cvt8(f32x4 a, f32x4 b) {
    short8 r;
    r[0] = (short)__builtin_bit_cast(unsigned short, __float2bfloat16(a[0]));
    r[1] = (short)__builtin_bit_cast(unsigned short, __float2bfloat16(a[1]));
    r[2] = (short)__builtin_bit_cast(unsigned short, __float2bfloat16(a[2]));
    r[3] = (short)__builtin_bit_cast(unsigned short, __float2bfloat16(a[3]));
    r[4] = (short)__builtin_bit_cast(unsigned short, __float2bfloat16(b[0]));
    r[5] = (short)__builtin_bit_cast(unsigned short, __float2bfloat16(b[1]));
    r[6] = (short)__builtin_bit_cast(unsigned short, __float2bfloat16(b[2]));
    r[7] = (short)__builtin_bit_cast(unsigned short, __float2bfloat16(b[3]));
    return r;
}

// ---- pass 0: W fp32 -> bf16, fragment-lane order ----
// Wpk element (e, g, kt32, l, j) = bf16(W[e][g*16 + (l&15)][kt32*32 + (l>>4)*8 + j])
// g = 16-row output group (32 per expert), kt32 = 32-wide k chunk (32 per expert).
__global__ __launch_bounds__(256)
void pack_w(const float* __restrict__ W, short* __restrict__ Wpk) {
    int idx  = blockIdx.x * 256 + threadIdx.x;  // 0 .. 8*32*32*64-1 = 524287
    int l    = idx & 63;
    int kt32 = (idx >> 6) & 31;
    int g    = (idx >> 11) & 31;
    int e    = idx >> 16;
    const float* src = W + (size_t)(e * NO + g * 16 + (l & 15)) * NI
                         + kt32 * 32 + (l >> 4) * 8;
    f32x4 a = *(const f32x4*)src;
    f32x4 b = *(const f32x4*)(src + 4);
    *(short8*)(Wpk + (size_t)idx * 8) = cvt8(a, b);
}

// ---- main grouped GEMM ----
__global__ __launch_bounds__(256, 3)
void moe_gemm(const float* __restrict__ X,
              const short* __restrict__ Wpk,
              float* __restrict__ Out) {
    // 2048 blocks = 8 experts * 64 mblks * 4 nblks; XCD-chunk swizzle:
    // each XCD owns one expert -> its 1 MB bf16 W stays L2-resident.
    int bid  = blockIdx.x;
    int swz  = (bid & 7) * 256 + (bid >> 3);
    int e    = swz >> 8;
    int rem  = swz & 255;
    int mblk = rem >> 2;   // nblk inner: 4 siblings share the same A tile
    int nblk = rem & 3;

    const float* Ap = X   + ((size_t)e * NS + (size_t)mblk * BM) * NI;
    const short* Bp = Wpk + (size_t)e * (32 * 32 * 64 * 8);
    float*       Cp = Out + ((size_t)e * NS + (size_t)mblk * BM) * NO + nblk * BN;

    __shared__ short lA[2][BM * BK];   // 16 KiB per buf, 32 KiB total

    const int tid  = threadIdx.x;
    const int lane = tid & 63;
    const int wid  = tid >> 6;
    const int wr   = (wid >> 1) * 64;            // wave row base (2x2 wave grid)
    const int wc   = (wid & 1) * 64;             // wave col base
    const int wcg  = nblk * 8 + (wid & 1) * 4;   // B fragment-group base
    const int l15  = lane & 15;
    const int l4   = lane >> 4;

    f32x4 acc[4][4];
#pragma unroll
    for (int i = 0; i < 4; ++i)
#pragma unroll
        for (int j = 0; j < 4; ++j)
            acc[i][j] = (f32x4){0.f, 0.f, 0.f, 0.f};

    // A staging: unit u = tid + i*256 (i=0..3), 8 floats each.
    // row = u>>3 (0..127), uc = u&7 (8-float chunk). Swizzle: phys = uc ^ (row&7).
    int ur[4], ucc[4], wofs[4];
#pragma unroll
    for (int i = 0; i < 4; ++i) {
        int u   = tid + i * 256;
        ur[i]   = u >> 3;
        ucc[i]  = u & 7;
        wofs[i] = ur[i] * BK + ((ucc[i] ^ (ur[i] & 7)) << 3);
    }

    f32x4 la[4][2];
    short8 bfr[2][4];

#define LOADT(kt)                                                              \
    do {                                                                       \
        _Pragma("unroll") for (int i = 0; i < 4; ++i) {                        \
            const f32x4* p = (const f32x4*)(Ap + (size_t)ur[i] * NI +          \
                                            (kt) * BK + ucc[i] * 8);           \
            la[i][0] = p[0];                                                   \
            la[i][1] = p[1];                                                   \
        }                                                                      \
    } while (0)

#define STAGE(buf)                                                             \
    do {                                                                       \
        _Pragma("unroll") for (int i = 0; i < 4; ++i)                          \
            *(short8*)&lA[buf][wofs[i]] = cvt8(la[i][0], la[i][1]);            \
    } while (0)

#define BLOAD(kt)                                                              \
    do {                                                                       \
        _Pragma("unroll") for (int kk = 0; kk < 2; ++kk)                       \
            _Pragma("unroll") for (int ni = 0; ni < 4; ++ni)                   \
                bfr[kk][ni] = *(const short8*)(Bp +                            \
                    ((size_t)((wcg + ni) * 32 + (kt) * 2 + kk) * 64 + lane) * 8); \
    } while (0)

#define COMPUTE(buf)                                                           \
    do {                                                                       \
        _Pragma("unroll") for (int kk = 0; kk < 2; ++kk) {                     \
            short8 af[4];                                                      \
            _Pragma("unroll") for (int mi = 0; mi < 4; ++mi) {                 \
                int row = wr + mi * 16 + l15;                                  \
                int cc  = ((kk * 4 + l4) ^ (row & 7)) << 3;                    \
                af[mi]  = *(const short8*)&lA[buf][row * BK + cc];             \
            }                                                                  \
            _Pragma("unroll") for (int mi = 0; mi < 4; ++mi)                   \
                _Pragma("unroll") for (int ni = 0; ni < 4; ++ni)               \
                    acc[mi][ni] = __builtin_amdgcn_mfma_f32_16x16x32_bf16(     \
                        af[mi], bfr[kk][ni], acc[mi][ni], 0, 0, 0);            \
        }                                                                      \
    } while (0)

    LOADT(0);
    STAGE(0);
    __syncthreads();
    int cur = 0;
#pragma unroll 1
    for (int kt = 0; kt < NT; ++kt) {
        BLOAD(kt);                           // L2-resident, reg-direct, no barrier dep
        if (kt + 1 < NT) LOADT(kt + 1);      // issue next A tile early
        COMPUTE(cur);
        if (kt + 1 < NT) STAGE(cur ^ 1);     // cvt + ds_write after compute
        __syncthreads();
        cur ^= 1;
    }

    // Epilogue: D[m][n], m = (lane>>4)*4 + r, n = lane&15 within each 16x16 frag.
#pragma unroll
    for (int mi = 0; mi < 4; ++mi) {
#pragma unroll
        for (int r = 0; r < 4; ++r) {
            int row   = wr + mi * 16 + l4 * 4 + r;
            float* cp = Cp + (size_t)row * NO + wc + l15;
#pragma unroll
            for (int ni = 0; ni < 4; ++ni)
                cp[ni * 16] = acc[mi][ni][r];
        }
    }
#undef LOADT
#undef STAGE
#undef BLOAD
#undef COMPUTE
}

extern "C" void kernel_launch(void* const* d_in, const int* in_sizes, int n_in,
                              void* d_out, int out_size, void* d_ws, size_t ws_size,
                              hipStream_t stream) {
    const float* X = (const float*)d_in[0];
    const float* W = (const float*)d_in[1];
    float* Out     = (float*)d_out;
    short* Wpk     = (short*)d_ws;   // needs 8 MiB

    // pass 0: 524288 short8 elements, 256 threads each -> 2048 blocks
    hipLaunchKernelGGL(pack_w, dim3(2048), dim3(256), 0, stream, W, Wpk);
    // pass 1: grouped GEMM
    hipLaunchKernelGGL(moe_gemm, dim3(NE * (NS / BM) * (NO / BN)), dim3(256), 0,
                       stream, X, Wpk, Out);
}